// Round 1
// baseline (312.960 us; speedup 1.0000x reference)
//
#include <hip/hip_runtime.h>
#include <hip/hip_bf16.h>

#define N_NODES 50000
#define N_EDGES 500000
#define H_DIM 128
#define OUT_DIM 16
#define KDIM 640  // 4*128 (bases) + 128 (self-loop features)

typedef short short8 __attribute__((ext_vector_type(8)));
typedef float f32x4 __attribute__((ext_vector_type(4)));

__device__ inline unsigned short f2b(float f) {
  unsigned u = __float_as_uint(f);
  u += 0x7fffu + ((u >> 16) & 1u);
  return (unsigned short)(u >> 16);
}

// ---------------- B-matrix pack: B1t [128][640], B2t [16][640] (transposed, bf16)
__global__ void prep_b_kernel(const float* __restrict__ basis1, const float* __restrict__ loop_w1,
                              const float* __restrict__ basis2, const float* __restrict__ loop_w2,
                              unsigned short* __restrict__ B1t, unsigned short* __restrict__ B2t) {
  int tid = blockIdx.x * blockDim.x + threadIdx.x;
  if (tid < 128 * KDIM) {
    int c = tid / KDIM, k = tid % KDIM;
    float v = (k < 512) ? basis1[k * 128 + c] : loop_w1[(k - 512) * 128 + c];
    B1t[c * KDIM + k] = f2b(v);
  } else if (tid < 128 * KDIM + 16 * KDIM) {
    int t2 = tid - 128 * KDIM;
    int c = t2 / KDIM, k = t2 % KDIM;
    float v = (k < 512) ? basis2[k * 16 + c] : loop_w2[(k - 512) * 16 + c];
    B2t[c * KDIM + k] = f2b(v);
  }
}

// ---------------- x = emb[node_ids] -> bf16 into Abuf[:, 512:640]
__global__ void convert_x_kernel(const int* __restrict__ node_ids, const float* __restrict__ emb,
                                 unsigned short* __restrict__ Abuf) {
  int tid = blockIdx.x * blockDim.x + threadIdx.x;  // one per 4 elems
  if (tid >= N_NODES * (H_DIM / 4)) return;
  int n = tid >> 5;
  int q = tid & 31;
  int id = node_ids[n];
  const float4 v = *reinterpret_cast<const float4*>(emb + (size_t)id * H_DIM + q * 4);
  uint2 p;
  p.x = (unsigned)f2b(v.x) | ((unsigned)f2b(v.y) << 16);
  p.y = (unsigned)f2b(v.z) | ((unsigned)f2b(v.w) << 16);
  *reinterpret_cast<uint2*>(Abuf + (size_t)n * KDIM + 512 + q * 4) = p;
}

// ---------------- CSR build
__global__ void count_kernel(const int* __restrict__ dst, int* __restrict__ cnt) {
  for (int e = blockIdx.x * blockDim.x + threadIdx.x; e < N_EDGES; e += gridDim.x * blockDim.x)
    atomicAdd(&cnt[dst[e]], 1);
}

__global__ void scan_kernel(const int* __restrict__ cnt, int* __restrict__ ptr) {
  __shared__ int part[1024];
  int t = threadIdx.x;
  const int n = N_NODES;
  const int chunk = (n + 1023) / 1024;
  int lo = t * chunk, hi = min(lo + chunk, n);
  int s = 0;
  for (int i = lo; i < hi; ++i) s += cnt[i];
  part[t] = s;
  __syncthreads();
  for (int off = 1; off < 1024; off <<= 1) {
    int v = (t >= off) ? part[t - off] : 0;
    __syncthreads();
    part[t] += v;
    __syncthreads();
  }
  int excl = (t == 0) ? 0 : part[t - 1];
  for (int i = lo; i < hi; ++i) { ptr[i] = excl; excl += cnt[i]; }
  if (t == 1023) ptr[n] = part[1023];
}

__global__ void fill_kernel(const int* __restrict__ src, const int* __restrict__ dst,
                            const int* __restrict__ et, const int* __restrict__ csr_ptr,
                            int* __restrict__ cnt, int* __restrict__ csr_src, int* __restrict__ csr_et) {
  for (int e = blockIdx.x * blockDim.x + threadIdx.x; e < N_EDGES; e += gridDim.x * blockDim.x) {
    int d = dst[e];
    int idx = csr_ptr[d] + atomicAdd(&cnt[d], 1);
    csr_src[idx] = src[e];
    csr_et[idx] = et[e];
  }
}

// ---------------- per-dst aggregation: y[d,b,i] = (1/deg) * sum_e comp[et,b]*feat[src,i]
// reads Abuf[:,512:640] (x or h), writes Abuf[:,0:512]. One wave per node.
__global__ __launch_bounds__(256) void agg_kernel(const int* __restrict__ csr_ptr,
                                                  const int* __restrict__ csr_src,
                                                  const int* __restrict__ csr_et,
                                                  const float* __restrict__ comp,
                                                  unsigned short* __restrict__ Abuf) {
  int node = blockIdx.x * 4 + (threadIdx.x >> 6);
  if (node >= N_NODES) return;
  int lane = threadIdx.x & 63;
  int lo = csr_ptr[node], hi = csr_ptr[node + 1];
  float acc[8] = {0.f, 0.f, 0.f, 0.f, 0.f, 0.f, 0.f, 0.f};
  for (int e = lo; e < hi; ++e) {
    int s = csr_src[e];
    int et = csr_et[e];
    const float4 c = *reinterpret_cast<const float4*>(comp + et * 4);
    unsigned u = *reinterpret_cast<const unsigned*>(Abuf + (size_t)s * KDIM + 512 + lane * 2);
    float x0 = __uint_as_float(u << 16);
    float x1 = __uint_as_float(u & 0xffff0000u);
    acc[0] += c.x * x0; acc[1] += c.x * x1;
    acc[2] += c.y * x0; acc[3] += c.y * x1;
    acc[4] += c.z * x0; acc[5] += c.z * x1;
    acc[6] += c.w * x0; acc[7] += c.w * x1;
  }
  int deg = hi - lo;
  float inv = 1.0f / (float)(deg > 0 ? deg : 1);
  unsigned short* out = Abuf + (size_t)node * KDIM;
#pragma unroll
  for (int b = 0; b < 4; ++b) {
    unsigned p = (unsigned)f2b(acc[b * 2] * inv) | ((unsigned)f2b(acc[b * 2 + 1] * inv) << 16);
    *reinterpret_cast<unsigned*>(out + b * 128 + lane * 2) = p;
  }
}

// ---------------- GEMM: C[M,NC] = A[M,640] * Bt[NC,640]^T (+bias, opt relu)
template <int NC, bool RELU, bool OUT_BF16>
__global__ __launch_bounds__(256) void gemm_kernel(const unsigned short* __restrict__ A,
                                                   const unsigned short* __restrict__ Bt,
                                                   const float* __restrict__ bias,
                                                   void* __restrict__ outp, int out_stride, int M) {
  __shared__ unsigned short As[64][64];
  __shared__ unsigned short Bs[NC][64];
  int wave = threadIdx.x >> 6;
  int lane = threadIdx.x & 63;
  int row0 = blockIdx.x * 64;
  f32x4 acc[NC / 16];
#pragma unroll
  for (int i = 0; i < NC / 16; ++i) acc[i] = (f32x4){0.f, 0.f, 0.f, 0.f};

  int ar = wave * 16 + (lane & 15);
  int kh = lane >> 4;  // 0..3, selects k-octet within K=32

  for (int k0 = 0; k0 < KDIM; k0 += 64) {
    // stage A tile 64x64 (XOR-swizzled 16B chunks)
#pragma unroll
    for (int p = 0; p < 2; ++p) {
      int cid = threadIdx.x + p * 256;
      int r = cid >> 3, c8 = cid & 7;
      int gr = row0 + r;
      short8 v = {};
      if (gr < M) v = *reinterpret_cast<const short8*>(A + (size_t)gr * KDIM + k0 + c8 * 8);
      *reinterpret_cast<short8*>(&As[r][(c8 ^ (r & 7)) * 8]) = v;
    }
    // stage B tile NCx64
    for (int cid = threadIdx.x; cid < NC * 8; cid += 256) {
      int r = cid >> 3, c8 = cid & 7;
      short8 v = *reinterpret_cast<const short8*>(Bt + (size_t)r * KDIM + k0 + c8 * 8);
      *reinterpret_cast<short8*>(&Bs[r][(c8 ^ (r & 7)) * 8]) = v;
    }
    __syncthreads();
    short8 a0 = *reinterpret_cast<const short8*>(&As[ar][((kh) ^ (ar & 7)) * 8]);
    short8 a1 = *reinterpret_cast<const short8*>(&As[ar][((4 + kh) ^ (ar & 7)) * 8]);
#pragma unroll
    for (int ct = 0; ct < NC / 16; ++ct) {
      int bc = ct * 16 + (lane & 15);
      short8 b0 = *reinterpret_cast<const short8*>(&Bs[bc][((kh) ^ (bc & 7)) * 8]);
      short8 b1 = *reinterpret_cast<const short8*>(&Bs[bc][((4 + kh) ^ (bc & 7)) * 8]);
      acc[ct] = __builtin_amdgcn_mfma_f32_16x16x32_bf16(a0, b0, acc[ct], 0, 0, 0);
      acc[ct] = __builtin_amdgcn_mfma_f32_16x16x32_bf16(a1, b1, acc[ct], 0, 0, 0);
    }
    __syncthreads();
  }
  // epilogue: D[row][col], col = lane&15, row = 4*(lane>>4)+r
  int col_l = lane & 15;
  int rb = row0 + wave * 16 + (lane >> 4) * 4;
#pragma unroll
  for (int ct = 0; ct < NC / 16; ++ct) {
    int col = ct * 16 + col_l;
    float bv = bias[col];
#pragma unroll
    for (int r = 0; r < 4; ++r) {
      int gr = rb + r;
      if (gr < M) {
        float v = acc[ct][r] + bv;
        if (RELU) v = fmaxf(v, 0.0f);
        if (OUT_BF16)
          reinterpret_cast<unsigned short*>(outp)[(size_t)gr * out_stride + col] = f2b(v);
        else
          reinterpret_cast<float*>(outp)[(size_t)gr * out_stride + col] = v;
      }
    }
  }
}

extern "C" void kernel_launch(void* const* d_in, const int* in_sizes, int n_in,
                              void* d_out, int out_size, void* d_ws, size_t ws_size,
                              hipStream_t stream) {
  const int* node_ids = (const int*)d_in[0];
  const int* src = (const int*)d_in[1];
  const int* dst = (const int*)d_in[2];
  const int* etype = (const int*)d_in[3];
  const float* emb = (const float*)d_in[4];
  const float* basis1 = (const float*)d_in[5];
  const float* comp1 = (const float*)d_in[6];
  const float* loop_w1 = (const float*)d_in[7];
  const float* bias1 = (const float*)d_in[8];
  const float* basis2 = (const float*)d_in[9];
  const float* comp2 = (const float*)d_in[10];
  const float* loop_w2 = (const float*)d_in[11];
  const float* bias2 = (const float*)d_in[12];
  (void)in_sizes; (void)n_in; (void)out_size; (void)ws_size;

  char* ws = (char*)d_ws;
  size_t off = 0;
  auto alloc = [&](size_t bytes) -> void* {
    void* p = ws + off;
    off += (bytes + 255) & ~(size_t)255;
    return p;
  };
  int* csr_ptr = (int*)alloc((N_NODES + 1) * sizeof(int));
  int* cntA = (int*)alloc(N_NODES * sizeof(int));
  int* cntB = (int*)alloc(N_NODES * sizeof(int));
  int* csr_src = (int*)alloc(N_EDGES * sizeof(int));
  int* csr_et = (int*)alloc(N_EDGES * sizeof(int));
  unsigned short* Abuf = (unsigned short*)alloc((size_t)N_NODES * KDIM * sizeof(unsigned short));
  unsigned short* B1t = (unsigned short*)alloc(128 * KDIM * sizeof(unsigned short));
  unsigned short* B2t = (unsigned short*)alloc(16 * KDIM * sizeof(unsigned short));

  hipMemsetAsync(cntA, 0, N_NODES * sizeof(int), stream);
  hipMemsetAsync(cntB, 0, N_NODES * sizeof(int), stream);

  prep_b_kernel<<<(144 * KDIM + 255) / 256, 256, 0, stream>>>(basis1, loop_w1, basis2, loop_w2, B1t, B2t);
  convert_x_kernel<<<(N_NODES * 32 + 255) / 256, 256, 0, stream>>>(node_ids, emb, Abuf);
  count_kernel<<<1024, 256, 0, stream>>>(dst, cntA);
  scan_kernel<<<1, 1024, 0, stream>>>(cntA, csr_ptr);
  fill_kernel<<<1024, 256, 0, stream>>>(src, dst, etype, csr_ptr, cntB, csr_src, csr_et);

  // layer 1: aggregate x -> y1s, then h = relu([y1s|x]*B1 + bias1) written into Abuf[:,512:640]
  agg_kernel<<<(N_NODES + 3) / 4, 256, 0, stream>>>(csr_ptr, csr_src, csr_et, comp1, Abuf);
  gemm_kernel<128, true, true><<<(N_NODES + 63) / 64, 256, 0, stream>>>(
      Abuf, B1t, bias1, Abuf + 512, KDIM, N_NODES);

  // layer 2: aggregate h -> y2s, then out = [y2s|h]*B2 + bias2 (fp32)
  agg_kernel<<<(N_NODES + 3) / 4, 256, 0, stream>>>(csr_ptr, csr_src, csr_et, comp2, Abuf);
  gemm_kernel<16, false, false><<<(N_NODES + 63) / 64, 256, 0, stream>>>(
      Abuf, B2t, bias2, d_out, OUT_DIM, N_NODES);
}

// Round 2
// 203.453 us; speedup vs baseline: 1.5382x; 1.5382x over previous
//
#include <hip/hip_runtime.h>
#include <hip/hip_bf16.h>

#define N_NODES 50000
#define N_EDGES 500000
#define H_DIM 128
#define OUT_DIM 16
#define KDIM 640  // 4*128 (bases) + 128 (self-loop features)

typedef short short8 __attribute__((ext_vector_type(8)));
typedef float f32x4 __attribute__((ext_vector_type(4)));

__device__ inline unsigned short f2b(float f) {
  unsigned u = __float_as_uint(f);
  u += 0x7fffu + ((u >> 16) & 1u);
  return (unsigned short)(u >> 16);
}

// ---------------- B-matrix pack: B1t [128][640], B2t [16][640] (transposed, bf16)
__global__ void prep_b_kernel(const float* __restrict__ basis1, const float* __restrict__ loop_w1,
                              const float* __restrict__ basis2, const float* __restrict__ loop_w2,
                              unsigned short* __restrict__ B1t, unsigned short* __restrict__ B2t) {
  int tid = blockIdx.x * blockDim.x + threadIdx.x;
  if (tid < 128 * KDIM) {
    int c = tid / KDIM, k = tid % KDIM;
    float v = (k < 512) ? basis1[k * 128 + c] : loop_w1[(k - 512) * 128 + c];
    B1t[c * KDIM + k] = f2b(v);
  } else if (tid < 128 * KDIM + 16 * KDIM) {
    int t2 = tid - 128 * KDIM;
    int c = t2 / KDIM, k = t2 % KDIM;
    float v = (k < 512) ? basis2[k * 16 + c] : loop_w2[(k - 512) * 16 + c];
    B2t[c * KDIM + k] = f2b(v);
  }
}

// ---------------- x = emb[node_ids] -> bf16 into Abuf[:, 512:640]
__global__ void convert_x_kernel(const int* __restrict__ node_ids, const float* __restrict__ emb,
                                 unsigned short* __restrict__ Abuf) {
  int tid = blockIdx.x * blockDim.x + threadIdx.x;  // one per 4 elems
  if (tid >= N_NODES * (H_DIM / 4)) return;
  int n = tid >> 5;
  int q = tid & 31;
  int id = node_ids[n];
  const float4 v = *reinterpret_cast<const float4*>(emb + (size_t)id * H_DIM + q * 4);
  uint2 p;
  p.x = (unsigned)f2b(v.x) | ((unsigned)f2b(v.y) << 16);
  p.y = (unsigned)f2b(v.z) | ((unsigned)f2b(v.w) << 16);
  *reinterpret_cast<uint2*>(Abuf + (size_t)n * KDIM + 512 + q * 4) = p;
}

// ---------------- CSR build (segment allocator; order-free, no serial scan)
__global__ void count_kernel(const int* __restrict__ dst, int* __restrict__ cnt) {
  for (int e = blockIdx.x * blockDim.x + threadIdx.x; e < N_EDGES; e += gridDim.x * blockDim.x)
    atomicAdd(&cnt[dst[e]], 1);
}

__global__ void alloc_kernel(const int* __restrict__ cnt, int* __restrict__ start,
                             int* __restrict__ counter) {
  int i = blockIdx.x * blockDim.x + threadIdx.x;
  int lane = threadIdx.x & 63;
  int c = (i < N_NODES) ? cnt[i] : 0;
  int incl = c;
#pragma unroll
  for (int off = 1; off < 64; off <<= 1) {
    int v = __shfl_up(incl, off, 64);
    if (lane >= off) incl += v;
  }
  int waveTotal = __shfl(incl, 63, 64);
  int base = 0;
  if (lane == 63) base = atomicAdd(counter, waveTotal);
  base = __shfl(base, 63, 64);
  if (i < N_NODES) start[i] = base + incl - c;
}

__global__ void fill_kernel(const int* __restrict__ src, const int* __restrict__ dst,
                            const int* __restrict__ et, const int* __restrict__ csr_start,
                            int* __restrict__ cnt, int2* __restrict__ csr_se) {
  for (int e = blockIdx.x * blockDim.x + threadIdx.x; e < N_EDGES; e += gridDim.x * blockDim.x) {
    int d = dst[e];
    int idx = csr_start[d] + atomicAdd(&cnt[d], 1);
    csr_se[idx] = make_int2(src[e], et[e]);
  }
}

// ---------------- per-dst aggregation: y[d,b,i] = (1/deg) * sum_e comp[et,b]*feat[src,i]
// reads Abuf[:,512:640] (x or h), writes Abuf[:,0:512]. One wave per node.
__global__ __launch_bounds__(256) void agg_kernel(const int* __restrict__ csr_start,
                                                  const int* __restrict__ csr_cnt,
                                                  const int2* __restrict__ csr_se,
                                                  const float* __restrict__ comp,
                                                  unsigned short* __restrict__ Abuf) {
  int node = blockIdx.x * 4 + (threadIdx.x >> 6);
  if (node >= N_NODES) return;
  int lane = threadIdx.x & 63;
  int lo = csr_start[node];
  int deg = csr_cnt[node];
  int hi = lo + deg;
  float acc[8] = {0.f, 0.f, 0.f, 0.f, 0.f, 0.f, 0.f, 0.f};

  const unsigned short* feat = Abuf + 512 + lane * 2;

  int e = lo;
  for (; e + 4 <= hi; e += 4) {
    int2 p0 = csr_se[e], p1 = csr_se[e + 1], p2 = csr_se[e + 2], p3 = csr_se[e + 3];
    unsigned u0 = *reinterpret_cast<const unsigned*>(feat + (size_t)p0.x * KDIM);
    unsigned u1 = *reinterpret_cast<const unsigned*>(feat + (size_t)p1.x * KDIM);
    unsigned u2 = *reinterpret_cast<const unsigned*>(feat + (size_t)p2.x * KDIM);
    unsigned u3 = *reinterpret_cast<const unsigned*>(feat + (size_t)p3.x * KDIM);
    float4 c0 = *reinterpret_cast<const float4*>(comp + p0.y * 4);
    float4 c1 = *reinterpret_cast<const float4*>(comp + p1.y * 4);
    float4 c2 = *reinterpret_cast<const float4*>(comp + p2.y * 4);
    float4 c3 = *reinterpret_cast<const float4*>(comp + p3.y * 4);
    float x0, x1;
    x0 = __uint_as_float(u0 << 16); x1 = __uint_as_float(u0 & 0xffff0000u);
    acc[0] += c0.x * x0; acc[1] += c0.x * x1; acc[2] += c0.y * x0; acc[3] += c0.y * x1;
    acc[4] += c0.z * x0; acc[5] += c0.z * x1; acc[6] += c0.w * x0; acc[7] += c0.w * x1;
    x0 = __uint_as_float(u1 << 16); x1 = __uint_as_float(u1 & 0xffff0000u);
    acc[0] += c1.x * x0; acc[1] += c1.x * x1; acc[2] += c1.y * x0; acc[3] += c1.y * x1;
    acc[4] += c1.z * x0; acc[5] += c1.z * x1; acc[6] += c1.w * x0; acc[7] += c1.w * x1;
    x0 = __uint_as_float(u2 << 16); x1 = __uint_as_float(u2 & 0xffff0000u);
    acc[0] += c2.x * x0; acc[1] += c2.x * x1; acc[2] += c2.y * x0; acc[3] += c2.y * x1;
    acc[4] += c2.z * x0; acc[5] += c2.z * x1; acc[6] += c2.w * x0; acc[7] += c2.w * x1;
    x0 = __uint_as_float(u3 << 16); x1 = __uint_as_float(u3 & 0xffff0000u);
    acc[0] += c3.x * x0; acc[1] += c3.x * x1; acc[2] += c3.y * x0; acc[3] += c3.y * x1;
    acc[4] += c3.z * x0; acc[5] += c3.z * x1; acc[6] += c3.w * x0; acc[7] += c3.w * x1;
  }
  for (; e < hi; ++e) {
    int2 p = csr_se[e];
    unsigned u = *reinterpret_cast<const unsigned*>(feat + (size_t)p.x * KDIM);
    float4 c = *reinterpret_cast<const float4*>(comp + p.y * 4);
    float x0 = __uint_as_float(u << 16);
    float x1 = __uint_as_float(u & 0xffff0000u);
    acc[0] += c.x * x0; acc[1] += c.x * x1; acc[2] += c.y * x0; acc[3] += c.y * x1;
    acc[4] += c.z * x0; acc[5] += c.z * x1; acc[6] += c.w * x0; acc[7] += c.w * x1;
  }

  float inv = 1.0f / (float)(deg > 0 ? deg : 1);
  unsigned short* out = Abuf + (size_t)node * KDIM;
#pragma unroll
  for (int b = 0; b < 4; ++b) {
    unsigned p = (unsigned)f2b(acc[b * 2] * inv) | ((unsigned)f2b(acc[b * 2 + 1] * inv) << 16);
    *reinterpret_cast<unsigned*>(out + b * 128 + lane * 2) = p;
  }
}

// ---------------- GEMM: C[M,NC] = A[M,640] * Bt[NC,640]^T (+bias, opt relu)
template <int NC, bool RELU, bool OUT_BF16>
__global__ __launch_bounds__(256) void gemm_kernel(const unsigned short* __restrict__ A,
                                                   const unsigned short* __restrict__ Bt,
                                                   const float* __restrict__ bias,
                                                   void* __restrict__ outp, int out_stride, int M) {
  __shared__ unsigned short As[64][64];
  __shared__ unsigned short Bs[NC][64];
  int wave = threadIdx.x >> 6;
  int lane = threadIdx.x & 63;
  int row0 = blockIdx.x * 64;
  f32x4 acc[NC / 16];
#pragma unroll
  for (int i = 0; i < NC / 16; ++i) acc[i] = (f32x4){0.f, 0.f, 0.f, 0.f};

  int ar = wave * 16 + (lane & 15);
  int kh = lane >> 4;  // 0..3, selects k-octet within K=32

  for (int k0 = 0; k0 < KDIM; k0 += 64) {
    // stage A tile 64x64 (XOR-swizzled 16B chunks)
#pragma unroll
    for (int p = 0; p < 2; ++p) {
      int cid = threadIdx.x + p * 256;
      int r = cid >> 3, c8 = cid & 7;
      int gr = row0 + r;
      short8 v = {};
      if (gr < M) v = *reinterpret_cast<const short8*>(A + (size_t)gr * KDIM + k0 + c8 * 8);
      *reinterpret_cast<short8*>(&As[r][(c8 ^ (r & 7)) * 8]) = v;
    }
    // stage B tile NCx64
    for (int cid = threadIdx.x; cid < NC * 8; cid += 256) {
      int r = cid >> 3, c8 = cid & 7;
      short8 v = *reinterpret_cast<const short8*>(Bt + (size_t)r * KDIM + k0 + c8 * 8);
      *reinterpret_cast<short8*>(&Bs[r][(c8 ^ (r & 7)) * 8]) = v;
    }
    __syncthreads();
    short8 a0 = *reinterpret_cast<const short8*>(&As[ar][((kh) ^ (ar & 7)) * 8]);
    short8 a1 = *reinterpret_cast<const short8*>(&As[ar][((4 + kh) ^ (ar & 7)) * 8]);
#pragma unroll
    for (int ct = 0; ct < NC / 16; ++ct) {
      int bc = ct * 16 + (lane & 15);
      short8 b0 = *reinterpret_cast<const short8*>(&Bs[bc][((kh) ^ (bc & 7)) * 8]);
      short8 b1 = *reinterpret_cast<const short8*>(&Bs[bc][((4 + kh) ^ (bc & 7)) * 8]);
      acc[ct] = __builtin_amdgcn_mfma_f32_16x16x32_bf16(a0, b0, acc[ct], 0, 0, 0);
      acc[ct] = __builtin_amdgcn_mfma_f32_16x16x32_bf16(a1, b1, acc[ct], 0, 0, 0);
    }
    __syncthreads();
  }
  // epilogue: D[row][col], col = lane&15, row = 4*(lane>>4)+r
  int col_l = lane & 15;
  int rb = row0 + wave * 16 + (lane >> 4) * 4;
#pragma unroll
  for (int ct = 0; ct < NC / 16; ++ct) {
    int col = ct * 16 + col_l;
    float bv = bias[col];
#pragma unroll
    for (int r = 0; r < 4; ++r) {
      int gr = rb + r;
      if (gr < M) {
        float v = acc[ct][r] + bv;
        if (RELU) v = fmaxf(v, 0.0f);
        if (OUT_BF16)
          reinterpret_cast<unsigned short*>(outp)[(size_t)gr * out_stride + col] = f2b(v);
        else
          reinterpret_cast<float*>(outp)[(size_t)gr * out_stride + col] = v;
      }
    }
  }
}

extern "C" void kernel_launch(void* const* d_in, const int* in_sizes, int n_in,
                              void* d_out, int out_size, void* d_ws, size_t ws_size,
                              hipStream_t stream) {
  const int* node_ids = (const int*)d_in[0];
  const int* src = (const int*)d_in[1];
  const int* dst = (const int*)d_in[2];
  const int* etype = (const int*)d_in[3];
  const float* emb = (const float*)d_in[4];
  const float* basis1 = (const float*)d_in[5];
  const float* comp1 = (const float*)d_in[6];
  const float* loop_w1 = (const float*)d_in[7];
  const float* bias1 = (const float*)d_in[8];
  const float* basis2 = (const float*)d_in[9];
  const float* comp2 = (const float*)d_in[10];
  const float* loop_w2 = (const float*)d_in[11];
  const float* bias2 = (const float*)d_in[12];
  (void)in_sizes; (void)n_in; (void)out_size; (void)ws_size;

  char* ws = (char*)d_ws;
  size_t off = 0;
  auto alloc = [&](size_t bytes) -> void* {
    void* p = ws + off;
    off += (bytes + 255) & ~(size_t)255;
    return p;
  };
  int* csr_start = (int*)alloc(N_NODES * sizeof(int));
  int* cntA = (int*)alloc(N_NODES * sizeof(int));
  int* cntB = (int*)alloc(N_NODES * sizeof(int));
  int* counter = (int*)alloc(sizeof(int));
  int2* csr_se = (int2*)alloc((size_t)N_EDGES * sizeof(int2));
  unsigned short* Abuf = (unsigned short*)alloc((size_t)N_NODES * KDIM * sizeof(unsigned short));
  unsigned short* B1t = (unsigned short*)alloc(128 * KDIM * sizeof(unsigned short));
  unsigned short* B2t = (unsigned short*)alloc(16 * KDIM * sizeof(unsigned short));

  hipMemsetAsync(cntA, 0, N_NODES * sizeof(int), stream);
  hipMemsetAsync(cntB, 0, N_NODES * sizeof(int), stream);
  hipMemsetAsync(counter, 0, sizeof(int), stream);

  prep_b_kernel<<<(144 * KDIM + 255) / 256, 256, 0, stream>>>(basis1, loop_w1, basis2, loop_w2, B1t, B2t);
  convert_x_kernel<<<(N_NODES * 32 + 255) / 256, 256, 0, stream>>>(node_ids, emb, Abuf);
  count_kernel<<<1024, 256, 0, stream>>>(dst, cntA);
  alloc_kernel<<<(N_NODES + 255) / 256, 256, 0, stream>>>(cntA, csr_start, counter);
  fill_kernel<<<1024, 256, 0, stream>>>(src, dst, etype, csr_start, cntB, csr_se);

  // layer 1: aggregate x -> y1s, then h = relu([y1s|x]*B1 + bias1) written into Abuf[:,512:640]
  agg_kernel<<<(N_NODES + 3) / 4, 256, 0, stream>>>(csr_start, cntA, csr_se, comp1, Abuf);
  gemm_kernel<128, true, true><<<(N_NODES + 63) / 64, 256, 0, stream>>>(
      Abuf, B1t, bias1, Abuf + 512, KDIM, N_NODES);

  // layer 2: aggregate h -> y2s, then out = [y2s|h]*B2 + bias2 (fp32)
  agg_kernel<<<(N_NODES + 3) / 4, 256, 0, stream>>>(csr_start, cntA, csr_se, comp2, Abuf);
  gemm_kernel<16, false, false><<<(N_NODES + 63) / 64, 256, 0, stream>>>(
      Abuf, B2t, bias2, d_out, OUT_DIM, N_NODES);
}

// Round 3
// 199.044 us; speedup vs baseline: 1.5723x; 1.0221x over previous
//
#include <hip/hip_runtime.h>
#include <hip/hip_bf16.h>

#define N_NODES 50000
#define N_EDGES 500000
#define H_DIM 128
#define OUT_DIM 16
#define KDIM 640  // 4*128 (bases) + 128 (self-loop features)

typedef short short8 __attribute__((ext_vector_type(8)));
typedef float f32x4 __attribute__((ext_vector_type(4)));

__device__ inline unsigned short f2b(float f) {
  unsigned u = __float_as_uint(f);
  u += 0x7fffu + ((u >> 16) & 1u);
  return (unsigned short)(u >> 16);
}

// ---------------- zero cntA, cntB, counter in one launch (replaces 3 hipMemsetAsync
// calls that each cost ~40us of rocclr fillBuffer overhead)
__global__ void init_kernel(int* __restrict__ cntA, int* __restrict__ cntB,
                            int* __restrict__ counter) {
  int i = blockIdx.x * blockDim.x + threadIdx.x;
  if (i < N_NODES) {
    cntA[i] = 0;
    cntB[i] = 0;
  }
  if (i == 0) *counter = 0;
}

// ---------------- B-matrix pack: B1t [128][640], B2t [16][640] (transposed, bf16)
__global__ void prep_b_kernel(const float* __restrict__ basis1, const float* __restrict__ loop_w1,
                              const float* __restrict__ basis2, const float* __restrict__ loop_w2,
                              unsigned short* __restrict__ B1t, unsigned short* __restrict__ B2t) {
  int tid = blockIdx.x * blockDim.x + threadIdx.x;
  if (tid < 128 * KDIM) {
    int c = tid / KDIM, k = tid % KDIM;
    float v = (k < 512) ? basis1[k * 128 + c] : loop_w1[(k - 512) * 128 + c];
    B1t[c * KDIM + k] = f2b(v);
  } else if (tid < 128 * KDIM + 16 * KDIM) {
    int t2 = tid - 128 * KDIM;
    int c = t2 / KDIM, k = t2 % KDIM;
    float v = (k < 512) ? basis2[k * 16 + c] : loop_w2[(k - 512) * 16 + c];
    B2t[c * KDIM + k] = f2b(v);
  }
}

// ---------------- x = emb[node_ids] -> bf16 into Abuf[:, 512:640]
__global__ void convert_x_kernel(const int* __restrict__ node_ids, const float* __restrict__ emb,
                                 unsigned short* __restrict__ Abuf) {
  int tid = blockIdx.x * blockDim.x + threadIdx.x;  // one per 4 elems
  if (tid >= N_NODES * (H_DIM / 4)) return;
  int n = tid >> 5;
  int q = tid & 31;
  int id = node_ids[n];
  const float4 v = *reinterpret_cast<const float4*>(emb + (size_t)id * H_DIM + q * 4);
  uint2 p;
  p.x = (unsigned)f2b(v.x) | ((unsigned)f2b(v.y) << 16);
  p.y = (unsigned)f2b(v.z) | ((unsigned)f2b(v.w) << 16);
  *reinterpret_cast<uint2*>(Abuf + (size_t)n * KDIM + 512 + q * 4) = p;
}

// ---------------- CSR build (segment allocator; order-free, no serial scan)
__global__ void count_kernel(const int* __restrict__ dst, int* __restrict__ cnt) {
  for (int e = blockIdx.x * blockDim.x + threadIdx.x; e < N_EDGES; e += gridDim.x * blockDim.x)
    atomicAdd(&cnt[dst[e]], 1);
}

__global__ void alloc_kernel(const int* __restrict__ cnt, int* __restrict__ start,
                             int* __restrict__ counter) {
  int i = blockIdx.x * blockDim.x + threadIdx.x;
  int lane = threadIdx.x & 63;
  int c = (i < N_NODES) ? cnt[i] : 0;
  int incl = c;
#pragma unroll
  for (int off = 1; off < 64; off <<= 1) {
    int v = __shfl_up(incl, off, 64);
    if (lane >= off) incl += v;
  }
  int waveTotal = __shfl(incl, 63, 64);
  int base = 0;
  if (lane == 63) base = atomicAdd(counter, waveTotal);
  base = __shfl(base, 63, 64);
  if (i < N_NODES) start[i] = base + incl - c;
}

__global__ void fill_kernel(const int* __restrict__ src, const int* __restrict__ dst,
                            const int* __restrict__ et, const int* __restrict__ csr_start,
                            int* __restrict__ cnt, int2* __restrict__ csr_se) {
  for (int e = blockIdx.x * blockDim.x + threadIdx.x; e < N_EDGES; e += gridDim.x * blockDim.x) {
    int d = dst[e];
    int idx = csr_start[d] + atomicAdd(&cnt[d], 1);
    csr_se[idx] = make_int2(src[e], et[e]);
  }
}

// ---------------- per-dst aggregation: y[d,b,i] = (1/deg) * sum_e comp[et,b]*feat[src,i]
// reads Abuf[:,512:640] (x or h), writes Abuf[:,0:512]. One wave per node.
__global__ __launch_bounds__(256) void agg_kernel(const int* __restrict__ csr_start,
                                                  const int* __restrict__ csr_cnt,
                                                  const int2* __restrict__ csr_se,
                                                  const float* __restrict__ comp,
                                                  unsigned short* __restrict__ Abuf) {
  int node = blockIdx.x * 4 + (threadIdx.x >> 6);
  if (node >= N_NODES) return;
  int lane = threadIdx.x & 63;
  int lo = csr_start[node];
  int deg = csr_cnt[node];
  int hi = lo + deg;
  float acc[8] = {0.f, 0.f, 0.f, 0.f, 0.f, 0.f, 0.f, 0.f};

  const unsigned short* feat = Abuf + 512 + lane * 2;

  int e = lo;
  for (; e + 4 <= hi; e += 4) {
    int2 p0 = csr_se[e], p1 = csr_se[e + 1], p2 = csr_se[e + 2], p3 = csr_se[e + 3];
    unsigned u0 = *reinterpret_cast<const unsigned*>(feat + (size_t)p0.x * KDIM);
    unsigned u1 = *reinterpret_cast<const unsigned*>(feat + (size_t)p1.x * KDIM);
    unsigned u2 = *reinterpret_cast<const unsigned*>(feat + (size_t)p2.x * KDIM);
    unsigned u3 = *reinterpret_cast<const unsigned*>(feat + (size_t)p3.x * KDIM);
    float4 c0 = *reinterpret_cast<const float4*>(comp + p0.y * 4);
    float4 c1 = *reinterpret_cast<const float4*>(comp + p1.y * 4);
    float4 c2 = *reinterpret_cast<const float4*>(comp + p2.y * 4);
    float4 c3 = *reinterpret_cast<const float4*>(comp + p3.y * 4);
    float x0, x1;
    x0 = __uint_as_float(u0 << 16); x1 = __uint_as_float(u0 & 0xffff0000u);
    acc[0] += c0.x * x0; acc[1] += c0.x * x1; acc[2] += c0.y * x0; acc[3] += c0.y * x1;
    acc[4] += c0.z * x0; acc[5] += c0.z * x1; acc[6] += c0.w * x0; acc[7] += c0.w * x1;
    x0 = __uint_as_float(u1 << 16); x1 = __uint_as_float(u1 & 0xffff0000u);
    acc[0] += c1.x * x0; acc[1] += c1.x * x1; acc[2] += c1.y * x0; acc[3] += c1.y * x1;
    acc[4] += c1.z * x0; acc[5] += c1.z * x1; acc[6] += c1.w * x0; acc[7] += c1.w * x1;
    x0 = __uint_as_float(u2 << 16); x1 = __uint_as_float(u2 & 0xffff0000u);
    acc[0] += c2.x * x0; acc[1] += c2.x * x1; acc[2] += c2.y * x0; acc[3] += c2.y * x1;
    acc[4] += c2.z * x0; acc[5] += c2.z * x1; acc[6] += c2.w * x0; acc[7] += c2.w * x1;
    x0 = __uint_as_float(u3 << 16); x1 = __uint_as_float(u3 & 0xffff0000u);
    acc[0] += c3.x * x0; acc[1] += c3.x * x1; acc[2] += c3.y * x0; acc[3] += c3.y * x1;
    acc[4] += c3.z * x0; acc[5] += c3.z * x1; acc[6] += c3.w * x0; acc[7] += c3.w * x1;
  }
  for (; e < hi; ++e) {
    int2 p = csr_se[e];
    unsigned u = *reinterpret_cast<const unsigned*>(feat + (size_t)p.x * KDIM);
    float4 c = *reinterpret_cast<const float4*>(comp + p.y * 4);
    float x0 = __uint_as_float(u << 16);
    float x1 = __uint_as_float(u & 0xffff0000u);
    acc[0] += c.x * x0; acc[1] += c.x * x1; acc[2] += c.y * x0; acc[3] += c.y * x1;
    acc[4] += c.z * x0; acc[5] += c.z * x1; acc[6] += c.w * x0; acc[7] += c.w * x1;
  }

  float inv = 1.0f / (float)(deg > 0 ? deg : 1);
  unsigned short* out = Abuf + (size_t)node * KDIM;
#pragma unroll
  for (int b = 0; b < 4; ++b) {
    unsigned p = (unsigned)f2b(acc[b * 2] * inv) | ((unsigned)f2b(acc[b * 2 + 1] * inv) << 16);
    *reinterpret_cast<unsigned*>(out + b * 128 + lane * 2) = p;
  }
}

// ---------------- GEMM: C[M,NC] = A[M,640] * Bt[NC,640]^T (+bias, opt relu)
template <int NC, bool RELU, bool OUT_BF16>
__global__ __launch_bounds__(256) void gemm_kernel(const unsigned short* __restrict__ A,
                                                   const unsigned short* __restrict__ Bt,
                                                   const float* __restrict__ bias,
                                                   void* __restrict__ outp, int out_stride, int M) {
  __shared__ unsigned short As[64][64];
  __shared__ unsigned short Bs[NC][64];
  int wave = threadIdx.x >> 6;
  int lane = threadIdx.x & 63;
  int row0 = blockIdx.x * 64;
  f32x4 acc[NC / 16];
#pragma unroll
  for (int i = 0; i < NC / 16; ++i) acc[i] = (f32x4){0.f, 0.f, 0.f, 0.f};

  int ar = wave * 16 + (lane & 15);
  int kh = lane >> 4;  // 0..3, selects k-octet within K=32

  for (int k0 = 0; k0 < KDIM; k0 += 64) {
    // stage A tile 64x64 (XOR-swizzled 16B chunks)
#pragma unroll
    for (int p = 0; p < 2; ++p) {
      int cid = threadIdx.x + p * 256;
      int r = cid >> 3, c8 = cid & 7;
      int gr = row0 + r;
      short8 v = {};
      if (gr < M) v = *reinterpret_cast<const short8*>(A + (size_t)gr * KDIM + k0 + c8 * 8);
      *reinterpret_cast<short8*>(&As[r][(c8 ^ (r & 7)) * 8]) = v;
    }
    // stage B tile NCx64
    for (int cid = threadIdx.x; cid < NC * 8; cid += 256) {
      int r = cid >> 3, c8 = cid & 7;
      short8 v = *reinterpret_cast<const short8*>(Bt + (size_t)r * KDIM + k0 + c8 * 8);
      *reinterpret_cast<short8*>(&Bs[r][(c8 ^ (r & 7)) * 8]) = v;
    }
    __syncthreads();
    short8 a0 = *reinterpret_cast<const short8*>(&As[ar][((kh) ^ (ar & 7)) * 8]);
    short8 a1 = *reinterpret_cast<const short8*>(&As[ar][((4 + kh) ^ (ar & 7)) * 8]);
#pragma unroll
    for (int ct = 0; ct < NC / 16; ++ct) {
      int bc = ct * 16 + (lane & 15);
      short8 b0 = *reinterpret_cast<const short8*>(&Bs[bc][((kh) ^ (bc & 7)) * 8]);
      short8 b1 = *reinterpret_cast<const short8*>(&Bs[bc][((4 + kh) ^ (bc & 7)) * 8]);
      acc[ct] = __builtin_amdgcn_mfma_f32_16x16x32_bf16(a0, b0, acc[ct], 0, 0, 0);
      acc[ct] = __builtin_amdgcn_mfma_f32_16x16x32_bf16(a1, b1, acc[ct], 0, 0, 0);
    }
    __syncthreads();
  }
  // epilogue: D[row][col], col = lane&15, row = 4*(lane>>4)+r
  int col_l = lane & 15;
  int rb = row0 + wave * 16 + (lane >> 4) * 4;
#pragma unroll
  for (int ct = 0; ct < NC / 16; ++ct) {
    int col = ct * 16 + col_l;
    float bv = bias[col];
#pragma unroll
    for (int r = 0; r < 4; ++r) {
      int gr = rb + r;
      if (gr < M) {
        float v = acc[ct][r] + bv;
        if (RELU) v = fmaxf(v, 0.0f);
        if (OUT_BF16)
          reinterpret_cast<unsigned short*>(outp)[(size_t)gr * out_stride + col] = f2b(v);
        else
          reinterpret_cast<float*>(outp)[(size_t)gr * out_stride + col] = v;
      }
    }
  }
}

extern "C" void kernel_launch(void* const* d_in, const int* in_sizes, int n_in,
                              void* d_out, int out_size, void* d_ws, size_t ws_size,
                              hipStream_t stream) {
  const int* node_ids = (const int*)d_in[0];
  const int* src = (const int*)d_in[1];
  const int* dst = (const int*)d_in[2];
  const int* etype = (const int*)d_in[3];
  const float* emb = (const float*)d_in[4];
  const float* basis1 = (const float*)d_in[5];
  const float* comp1 = (const float*)d_in[6];
  const float* loop_w1 = (const float*)d_in[7];
  const float* bias1 = (const float*)d_in[8];
  const float* basis2 = (const float*)d_in[9];
  const float* comp2 = (const float*)d_in[10];
  const float* loop_w2 = (const float*)d_in[11];
  const float* bias2 = (const float*)d_in[12];
  (void)in_sizes; (void)n_in; (void)out_size; (void)ws_size;

  char* ws = (char*)d_ws;
  size_t off = 0;
  auto alloc = [&](size_t bytes) -> void* {
    void* p = ws + off;
    off += (bytes + 255) & ~(size_t)255;
    return p;
  };
  int* csr_start = (int*)alloc(N_NODES * sizeof(int));
  int* cntA = (int*)alloc(N_NODES * sizeof(int));
  int* cntB = (int*)alloc(N_NODES * sizeof(int));
  int* counter = (int*)alloc(sizeof(int));
  int2* csr_se = (int2*)alloc((size_t)N_EDGES * sizeof(int2));
  unsigned short* Abuf = (unsigned short*)alloc((size_t)N_NODES * KDIM * sizeof(unsigned short));
  unsigned short* B1t = (unsigned short*)alloc(128 * KDIM * sizeof(unsigned short));
  unsigned short* B2t = (unsigned short*)alloc(16 * KDIM * sizeof(unsigned short));

  init_kernel<<<(N_NODES + 255) / 256, 256, 0, stream>>>(cntA, cntB, counter);
  prep_b_kernel<<<(144 * KDIM + 255) / 256, 256, 0, stream>>>(basis1, loop_w1, basis2, loop_w2, B1t, B2t);
  convert_x_kernel<<<(N_NODES * 32 + 255) / 256, 256, 0, stream>>>(node_ids, emb, Abuf);
  count_kernel<<<1024, 256, 0, stream>>>(dst, cntA);
  alloc_kernel<<<(N_NODES + 255) / 256, 256, 0, stream>>>(cntA, csr_start, counter);
  fill_kernel<<<1024, 256, 0, stream>>>(src, dst, etype, csr_start, cntB, csr_se);

  // layer 1: aggregate x -> y1s, then h = relu([y1s|x]*B1 + bias1) written into Abuf[:,512:640]
  agg_kernel<<<(N_NODES + 3) / 4, 256, 0, stream>>>(csr_start, cntA, csr_se, comp1, Abuf);
  gemm_kernel<128, true, true><<<(N_NODES + 63) / 64, 256, 0, stream>>>(
      Abuf, B1t, bias1, Abuf + 512, KDIM, N_NODES);

  // layer 2: aggregate h -> y2s, then out = [y2s|h]*B2 + bias2 (fp32)
  agg_kernel<<<(N_NODES + 3) / 4, 256, 0, stream>>>(csr_start, cntA, csr_se, comp2, Abuf);
  gemm_kernel<16, false, false><<<(N_NODES + 63) / 64, 256, 0, stream>>>(
      Abuf, B2t, bias2, d_out, OUT_DIM, N_NODES);
}

// Round 4
// 175.663 us; speedup vs baseline: 1.7816x; 1.1331x over previous
//
#include <hip/hip_runtime.h>
#include <hip/hip_bf16.h>

#define N_NODES 50000
#define N_EDGES 500000
#define H_DIM 128
#define OUT_DIM 16
#define KDIM 640  // 4*128 (bases) + 128 (self-loop features)

typedef short short8 __attribute__((ext_vector_type(8)));
typedef float f32x4 __attribute__((ext_vector_type(4)));
typedef float f32x2 __attribute__((ext_vector_type(2)));

__device__ inline unsigned short f2b(float f) {
  unsigned u = __float_as_uint(f);
  u += 0x7fffu + ((u >> 16) & 1u);
  return (unsigned short)(u >> 16);
}

// ---------------- fused prologue: convert_x | prep_b | init counters
// blocks [0, 6250): x = emb[node_ids] -> bf16 into Abuf[:,512:640]
// blocks [6250, 6610): pack B1t [128][640], B2t [16][640]
// blocks [6610, 6806): zero cntA/cntB/counter
#define CONV_BLOCKS 6250
#define PREP_BLOCKS 360
#define INIT_BLOCKS 196
__global__ void prologue_kernel(const int* __restrict__ node_ids, const float* __restrict__ emb,
                                unsigned short* __restrict__ Abuf,
                                const float* __restrict__ basis1, const float* __restrict__ loop_w1,
                                const float* __restrict__ basis2, const float* __restrict__ loop_w2,
                                unsigned short* __restrict__ B1t, unsigned short* __restrict__ B2t,
                                int* __restrict__ cntA, int* __restrict__ cntB,
                                int* __restrict__ counter) {
  int b = blockIdx.x;
  if (b < CONV_BLOCKS) {
    int tid = b * 256 + threadIdx.x;  // one per 4 elems
    if (tid >= N_NODES * (H_DIM / 4)) return;
    int n = tid >> 5;
    int q = tid & 31;
    int id = node_ids[n];
    const float4 v = *reinterpret_cast<const float4*>(emb + (size_t)id * H_DIM + q * 4);
    uint2 p;
    p.x = (unsigned)f2b(v.x) | ((unsigned)f2b(v.y) << 16);
    p.y = (unsigned)f2b(v.z) | ((unsigned)f2b(v.w) << 16);
    *reinterpret_cast<uint2*>(Abuf + (size_t)n * KDIM + 512 + q * 4) = p;
  } else if (b < CONV_BLOCKS + PREP_BLOCKS) {
    int tid = (b - CONV_BLOCKS) * 256 + threadIdx.x;
    if (tid < 128 * KDIM) {
      int c = tid / KDIM, k = tid % KDIM;
      float v = (k < 512) ? basis1[k * 128 + c] : loop_w1[(k - 512) * 128 + c];
      B1t[c * KDIM + k] = f2b(v);
    } else if (tid < 144 * KDIM) {
      int t2 = tid - 128 * KDIM;
      int c = t2 / KDIM, k = t2 % KDIM;
      float v = (k < 512) ? basis2[k * 16 + c] : loop_w2[(k - 512) * 16 + c];
      B2t[c * KDIM + k] = f2b(v);
    }
  } else {
    int i = (b - CONV_BLOCKS - PREP_BLOCKS) * 256 + threadIdx.x;
    if (i < N_NODES) {
      cntA[i] = 0;
      cntB[i] = 0;
    }
    if (i == 0) *counter = 0;
  }
}

// ---------------- CSR build (segment allocator; order-free)
__global__ void count_kernel(const int* __restrict__ dst, int* __restrict__ cnt) {
  for (int e = blockIdx.x * blockDim.x + threadIdx.x; e < N_EDGES; e += gridDim.x * blockDim.x)
    atomicAdd(&cnt[dst[e]], 1);
}

__global__ void alloc_kernel(const int* __restrict__ cnt, int* __restrict__ start,
                             int* __restrict__ counter) {
  int i = blockIdx.x * blockDim.x + threadIdx.x;
  int lane = threadIdx.x & 63;
  int c = (i < N_NODES) ? cnt[i] : 0;
  int incl = c;
#pragma unroll
  for (int off = 1; off < 64; off <<= 1) {
    int v = __shfl_up(incl, off, 64);
    if (lane >= off) incl += v;
  }
  int waveTotal = __shfl(incl, 63, 64);
  int base = 0;
  if (lane == 63) base = atomicAdd(counter, waveTotal);
  base = __shfl(base, 63, 64);
  if (i < N_NODES) start[i] = base + incl - c;
}

__global__ void fill_kernel(const int* __restrict__ src, const int* __restrict__ dst,
                            const int* __restrict__ et, const int* __restrict__ csr_start,
                            int* __restrict__ cnt, int2* __restrict__ csr_se) {
  for (int e = blockIdx.x * blockDim.x + threadIdx.x; e < N_EDGES; e += gridDim.x * blockDim.x) {
    int d = dst[e];
    int idx = csr_start[d] + atomicAdd(&cnt[d], 1);
    csr_se[idx] = make_int2(src[e], et[e]);
  }
}

// ---------------- per-dst aggregation: y[d,b,i] = (1/deg) * sum_e comp[et,b]*feat[src,i]
// One wave per node. Edge records scalarized via readfirstlane -> SGPR row base,
// gather is global_load_dword with constant lane offset; FMAs packed (v_pk_fma_f32).
__global__ __launch_bounds__(256) void agg_kernel(const int* __restrict__ csr_start,
                                                  const int* __restrict__ csr_cnt,
                                                  const int2* __restrict__ csr_se,
                                                  const float* __restrict__ comp,
                                                  unsigned short* __restrict__ Abuf) {
  int node = blockIdx.x * 4 + (threadIdx.x >> 6);
  if (node >= N_NODES) return;
  int lane = threadIdx.x & 63;
  int lo = __builtin_amdgcn_readfirstlane(csr_start[node]);
  int deg = __builtin_amdgcn_readfirstlane(csr_cnt[node]);
  int hi = lo + deg;

  f32x2 a0 = {0.f, 0.f}, a1 = {0.f, 0.f}, a2 = {0.f, 0.f}, a3 = {0.f, 0.f};
  const unsigned short* featb = Abuf + 512;
  const int laneoff = lane * 2;  // elements

#define EDGE_BODY(S, T)                                                              \
  {                                                                                  \
    unsigned u = *reinterpret_cast<const unsigned*>(featb + (size_t)(S)*KDIM + laneoff); \
    float4 c = *reinterpret_cast<const float4*>(comp + (T)*4);                       \
    f32x2 x;                                                                         \
    x.x = __uint_as_float(u << 16);                                                  \
    x.y = __uint_as_float(u & 0xffff0000u);                                          \
    a0 = __builtin_elementwise_fma((f32x2){c.x, c.x}, x, a0);                        \
    a1 = __builtin_elementwise_fma((f32x2){c.y, c.y}, x, a1);                        \
    a2 = __builtin_elementwise_fma((f32x2){c.z, c.z}, x, a2);                        \
    a3 = __builtin_elementwise_fma((f32x2){c.w, c.w}, x, a3);                        \
  }

  int e = lo;
  for (; e + 4 <= hi; e += 4) {
    int2 p0 = csr_se[e], p1 = csr_se[e + 1], p2 = csr_se[e + 2], p3 = csr_se[e + 3];
    int s0 = __builtin_amdgcn_readfirstlane(p0.x), t0 = __builtin_amdgcn_readfirstlane(p0.y);
    int s1 = __builtin_amdgcn_readfirstlane(p1.x), t1 = __builtin_amdgcn_readfirstlane(p1.y);
    int s2 = __builtin_amdgcn_readfirstlane(p2.x), t2 = __builtin_amdgcn_readfirstlane(p2.y);
    int s3 = __builtin_amdgcn_readfirstlane(p3.x), t3 = __builtin_amdgcn_readfirstlane(p3.y);
    EDGE_BODY(s0, t0)
    EDGE_BODY(s1, t1)
    EDGE_BODY(s2, t2)
    EDGE_BODY(s3, t3)
  }
  for (; e < hi; ++e) {
    int2 p = csr_se[e];
    int s0 = __builtin_amdgcn_readfirstlane(p.x), t0 = __builtin_amdgcn_readfirstlane(p.y);
    EDGE_BODY(s0, t0)
  }
#undef EDGE_BODY

  float inv = 1.0f / (float)(deg > 0 ? deg : 1);
  unsigned short* out = Abuf + (size_t)node * KDIM;
  unsigned p0w = (unsigned)f2b(a0.x * inv) | ((unsigned)f2b(a0.y * inv) << 16);
  unsigned p1w = (unsigned)f2b(a1.x * inv) | ((unsigned)f2b(a1.y * inv) << 16);
  unsigned p2w = (unsigned)f2b(a2.x * inv) | ((unsigned)f2b(a2.y * inv) << 16);
  unsigned p3w = (unsigned)f2b(a3.x * inv) | ((unsigned)f2b(a3.y * inv) << 16);
  *reinterpret_cast<unsigned*>(out + 0 * 128 + laneoff) = p0w;
  *reinterpret_cast<unsigned*>(out + 1 * 128 + laneoff) = p1w;
  *reinterpret_cast<unsigned*>(out + 2 * 128 + laneoff) = p2w;
  *reinterpret_cast<unsigned*>(out + 3 * 128 + laneoff) = p3w;
}

// ---------------- GEMM: C[M,NC] = A[M,640] * Bt[NC,640]^T (+bias, opt relu)
template <int NC, bool RELU, bool OUT_BF16>
__global__ __launch_bounds__(256) void gemm_kernel(const unsigned short* __restrict__ A,
                                                   const unsigned short* __restrict__ Bt,
                                                   const float* __restrict__ bias,
                                                   void* __restrict__ outp, int out_stride, int M) {
  __shared__ unsigned short As[64][64];
  __shared__ unsigned short Bs[NC][64];
  int wave = threadIdx.x >> 6;
  int lane = threadIdx.x & 63;
  int row0 = blockIdx.x * 64;
  f32x4 acc[NC / 16];
#pragma unroll
  for (int i = 0; i < NC / 16; ++i) acc[i] = (f32x4){0.f, 0.f, 0.f, 0.f};

  int ar = wave * 16 + (lane & 15);
  int kh = lane >> 4;  // 0..3, selects k-octet within K=32

  for (int k0 = 0; k0 < KDIM; k0 += 64) {
#pragma unroll
    for (int p = 0; p < 2; ++p) {
      int cid = threadIdx.x + p * 256;
      int r = cid >> 3, c8 = cid & 7;
      int gr = row0 + r;
      short8 v = {};
      if (gr < M) v = *reinterpret_cast<const short8*>(A + (size_t)gr * KDIM + k0 + c8 * 8);
      *reinterpret_cast<short8*>(&As[r][(c8 ^ (r & 7)) * 8]) = v;
    }
    for (int cid = threadIdx.x; cid < NC * 8; cid += 256) {
      int r = cid >> 3, c8 = cid & 7;
      short8 v = *reinterpret_cast<const short8*>(Bt + (size_t)r * KDIM + k0 + c8 * 8);
      *reinterpret_cast<short8*>(&Bs[r][(c8 ^ (r & 7)) * 8]) = v;
    }
    __syncthreads();
    short8 a0 = *reinterpret_cast<const short8*>(&As[ar][((kh) ^ (ar & 7)) * 8]);
    short8 a1 = *reinterpret_cast<const short8*>(&As[ar][((4 + kh) ^ (ar & 7)) * 8]);
#pragma unroll
    for (int ct = 0; ct < NC / 16; ++ct) {
      int bc = ct * 16 + (lane & 15);
      short8 b0 = *reinterpret_cast<const short8*>(&Bs[bc][((kh) ^ (bc & 7)) * 8]);
      short8 b1 = *reinterpret_cast<const short8*>(&Bs[bc][((4 + kh) ^ (bc & 7)) * 8]);
      acc[ct] = __builtin_amdgcn_mfma_f32_16x16x32_bf16(a0, b0, acc[ct], 0, 0, 0);
      acc[ct] = __builtin_amdgcn_mfma_f32_16x16x32_bf16(a1, b1, acc[ct], 0, 0, 0);
    }
    __syncthreads();
  }
  int col_l = lane & 15;
  int rb = row0 + wave * 16 + (lane >> 4) * 4;
#pragma unroll
  for (int ct = 0; ct < NC / 16; ++ct) {
    int col = ct * 16 + col_l;
    float bv = bias[col];
#pragma unroll
    for (int r = 0; r < 4; ++r) {
      int gr = rb + r;
      if (gr < M) {
        float v = acc[ct][r] + bv;
        if (RELU) v = fmaxf(v, 0.0f);
        if (OUT_BF16)
          reinterpret_cast<unsigned short*>(outp)[(size_t)gr * out_stride + col] = f2b(v);
        else
          reinterpret_cast<float*>(outp)[(size_t)gr * out_stride + col] = v;
      }
    }
  }
}

extern "C" void kernel_launch(void* const* d_in, const int* in_sizes, int n_in,
                              void* d_out, int out_size, void* d_ws, size_t ws_size,
                              hipStream_t stream) {
  const int* node_ids = (const int*)d_in[0];
  const int* src = (const int*)d_in[1];
  const int* dst = (const int*)d_in[2];
  const int* etype = (const int*)d_in[3];
  const float* emb = (const float*)d_in[4];
  const float* basis1 = (const float*)d_in[5];
  const float* comp1 = (const float*)d_in[6];
  const float* loop_w1 = (const float*)d_in[7];
  const float* bias1 = (const float*)d_in[8];
  const float* basis2 = (const float*)d_in[9];
  const float* comp2 = (const float*)d_in[10];
  const float* loop_w2 = (const float*)d_in[11];
  const float* bias2 = (const float*)d_in[12];
  (void)in_sizes; (void)n_in; (void)out_size; (void)ws_size;

  char* ws = (char*)d_ws;
  size_t off = 0;
  auto alloc = [&](size_t bytes) -> void* {
    void* p = ws + off;
    off += (bytes + 255) & ~(size_t)255;
    return p;
  };
  int* csr_start = (int*)alloc(N_NODES * sizeof(int));
  int* cntA = (int*)alloc(N_NODES * sizeof(int));
  int* cntB = (int*)alloc(N_NODES * sizeof(int));
  int* counter = (int*)alloc(sizeof(int));
  int2* csr_se = (int2*)alloc((size_t)N_EDGES * sizeof(int2));
  unsigned short* Abuf = (unsigned short*)alloc((size_t)N_NODES * KDIM * sizeof(unsigned short));
  unsigned short* B1t = (unsigned short*)alloc(128 * KDIM * sizeof(unsigned short));
  unsigned short* B2t = (unsigned short*)alloc(16 * KDIM * sizeof(unsigned short));

  prologue_kernel<<<CONV_BLOCKS + PREP_BLOCKS + INIT_BLOCKS, 256, 0, stream>>>(
      node_ids, emb, Abuf, basis1, loop_w1, basis2, loop_w2, B1t, B2t, cntA, cntB, counter);
  count_kernel<<<1024, 256, 0, stream>>>(dst, cntA);
  alloc_kernel<<<(N_NODES + 255) / 256, 256, 0, stream>>>(cntA, csr_start, counter);
  fill_kernel<<<1024, 256, 0, stream>>>(src, dst, etype, csr_start, cntB, csr_se);

  // layer 1: aggregate x -> y1s, then h = relu([y1s|x]*B1 + bias1) into Abuf[:,512:640]
  agg_kernel<<<(N_NODES + 3) / 4, 256, 0, stream>>>(csr_start, cntA, csr_se, comp1, Abuf);
  gemm_kernel<128, true, true><<<(N_NODES + 63) / 64, 256, 0, stream>>>(
      Abuf, B1t, bias1, Abuf + 512, KDIM, N_NODES);

  // layer 2: aggregate h -> y2s, then out = [y2s|h]*B2 + bias2 (fp32)
  agg_kernel<<<(N_NODES + 3) / 4, 256, 0, stream>>>(csr_start, cntA, csr_se, comp2, Abuf);
  gemm_kernel<16, false, false><<<(N_NODES + 63) / 64, 256, 0, stream>>>(
      Abuf, B2t, bias2, d_out, OUT_DIM, N_NODES);
}

// Round 5
// 166.858 us; speedup vs baseline: 1.8756x; 1.0528x over previous
//
#include <hip/hip_runtime.h>
#include <hip/hip_bf16.h>

#define N_NODES 50000
#define N_EDGES 500000
#define H_DIM 128
#define OUT_DIM 16
#define KDIM 640  // 4*128 (bases) + 128 (self-loop features)

typedef short short8 __attribute__((ext_vector_type(8)));
typedef float f32x4 __attribute__((ext_vector_type(4)));
typedef float f32x2 __attribute__((ext_vector_type(2)));

__device__ inline unsigned short f2b(float f) {
  unsigned u = __float_as_uint(f);
  u += 0x7fffu + ((u >> 16) & 1u);
  return (unsigned short)(u >> 16);
}
__device__ inline float b2f(unsigned short u) {
  return __uint_as_float(((unsigned)u) << 16);
}

// ---------------- fused prologue: convert_x | pack B1t [128][640] + B2pt [80][128] | init
// B2pt row c (<64): basis2[b=c>>4][k][o=c&15]; row c in [64,80): loop_w2[k][c-64].
#define CONV_BLOCKS 6250
#define PREP_BLOCKS 360
#define INIT_BLOCKS 196
__global__ void prologue_kernel(const int* __restrict__ node_ids, const float* __restrict__ emb,
                                unsigned short* __restrict__ Abuf,
                                const float* __restrict__ basis1, const float* __restrict__ loop_w1,
                                const float* __restrict__ basis2, const float* __restrict__ loop_w2,
                                unsigned short* __restrict__ B1t, unsigned short* __restrict__ B2pt,
                                int* __restrict__ cntA, int* __restrict__ cntB,
                                int* __restrict__ counter) {
  int b = blockIdx.x;
  if (b < CONV_BLOCKS) {
    int tid = b * 256 + threadIdx.x;  // one per 4 elems
    if (tid >= N_NODES * (H_DIM / 4)) return;
    int n = tid >> 5;
    int q = tid & 31;
    int id = node_ids[n];
    const float4 v = *reinterpret_cast<const float4*>(emb + (size_t)id * H_DIM + q * 4);
    uint2 p;
    p.x = (unsigned)f2b(v.x) | ((unsigned)f2b(v.y) << 16);
    p.y = (unsigned)f2b(v.z) | ((unsigned)f2b(v.w) << 16);
    *reinterpret_cast<uint2*>(Abuf + (size_t)n * KDIM + 512 + q * 4) = p;
  } else if (b < CONV_BLOCKS + PREP_BLOCKS) {
    int tid = (b - CONV_BLOCKS) * 256 + threadIdx.x;
    if (tid < 128 * KDIM) {
      int c = tid / KDIM, k = tid % KDIM;
      float v = (k < 512) ? basis1[k * 128 + c] : loop_w1[(k - 512) * 128 + c];
      B1t[c * KDIM + k] = f2b(v);
    } else if (tid < 128 * KDIM + 80 * 128) {
      int t2 = tid - 128 * KDIM;
      int c = t2 / 128, k = t2 % 128;
      float v = (c < 64) ? basis2[(c >> 4) * 128 * 16 + k * 16 + (c & 15)]
                         : loop_w2[k * 16 + (c - 64)];
      B2pt[c * 128 + k] = f2b(v);
    }
  } else {
    int i = (b - CONV_BLOCKS - PREP_BLOCKS) * 256 + threadIdx.x;
    if (i < N_NODES) {
      cntA[i] = 0;
      cntB[i] = 0;
    }
    if (i == 0) *counter = 0;
  }
}

// ---------------- CSR build (segment allocator; order-free)
__global__ void count_kernel(const int* __restrict__ dst, int* __restrict__ cnt) {
  for (int e = blockIdx.x * blockDim.x + threadIdx.x; e < N_EDGES; e += gridDim.x * blockDim.x)
    atomicAdd(&cnt[dst[e]], 1);
}

__global__ void alloc_kernel(const int* __restrict__ cnt, int* __restrict__ start,
                             int* __restrict__ counter) {
  int i = blockIdx.x * blockDim.x + threadIdx.x;
  int lane = threadIdx.x & 63;
  int c = (i < N_NODES) ? cnt[i] : 0;
  int incl = c;
#pragma unroll
  for (int off = 1; off < 64; off <<= 1) {
    int v = __shfl_up(incl, off, 64);
    if (lane >= off) incl += v;
  }
  int waveTotal = __shfl(incl, 63, 64);
  int base = 0;
  if (lane == 63) base = atomicAdd(counter, waveTotal);
  base = __shfl(base, 63, 64);
  if (i < N_NODES) start[i] = base + incl - c;
}

__global__ void fill_kernel(const int* __restrict__ src, const int* __restrict__ dst,
                            const int* __restrict__ et, const int* __restrict__ csr_start,
                            int* __restrict__ cnt, int2* __restrict__ csr_se) {
  for (int e = blockIdx.x * blockDim.x + threadIdx.x; e < N_EDGES; e += gridDim.x * blockDim.x) {
    int d = dst[e];
    int idx = csr_start[d] + atomicAdd(&cnt[d], 1);
    csr_se[idx] = make_int2(src[e], et[e]);
  }
}

// ---------------- layer-1 aggregation: y[d,b,i] = (1/deg) * sum_e comp[et,b]*x[src,i]
// One wave per node; reads Abuf[:,512:640], writes Abuf[:,0:512].
__global__ __launch_bounds__(256) void agg_kernel(const int* __restrict__ csr_start,
                                                  const int* __restrict__ csr_cnt,
                                                  const int2* __restrict__ csr_se,
                                                  const float* __restrict__ comp,
                                                  unsigned short* __restrict__ Abuf) {
  int node = blockIdx.x * 4 + (threadIdx.x >> 6);
  if (node >= N_NODES) return;
  int lane = threadIdx.x & 63;
  int lo = __builtin_amdgcn_readfirstlane(csr_start[node]);
  int deg = __builtin_amdgcn_readfirstlane(csr_cnt[node]);
  int hi = lo + deg;

  f32x2 a0 = {0.f, 0.f}, a1 = {0.f, 0.f}, a2 = {0.f, 0.f}, a3 = {0.f, 0.f};
  const unsigned short* featb = Abuf + 512;
  const int laneoff = lane * 2;  // elements

#define EDGE_BODY(S, T)                                                              \
  {                                                                                  \
    unsigned u = *reinterpret_cast<const unsigned*>(featb + (size_t)(S)*KDIM + laneoff); \
    float4 c = *reinterpret_cast<const float4*>(comp + (T)*4);                       \
    f32x2 x;                                                                         \
    x.x = __uint_as_float(u << 16);                                                  \
    x.y = __uint_as_float(u & 0xffff0000u);                                          \
    a0 = __builtin_elementwise_fma((f32x2){c.x, c.x}, x, a0);                        \
    a1 = __builtin_elementwise_fma((f32x2){c.y, c.y}, x, a1);                        \
    a2 = __builtin_elementwise_fma((f32x2){c.z, c.z}, x, a2);                        \
    a3 = __builtin_elementwise_fma((f32x2){c.w, c.w}, x, a3);                        \
  }

  int e = lo;
  for (; e + 4 <= hi; e += 4) {
    int2 p0 = csr_se[e], p1 = csr_se[e + 1], p2 = csr_se[e + 2], p3 = csr_se[e + 3];
    int s0 = __builtin_amdgcn_readfirstlane(p0.x), t0 = __builtin_amdgcn_readfirstlane(p0.y);
    int s1 = __builtin_amdgcn_readfirstlane(p1.x), t1 = __builtin_amdgcn_readfirstlane(p1.y);
    int s2 = __builtin_amdgcn_readfirstlane(p2.x), t2 = __builtin_amdgcn_readfirstlane(p2.y);
    int s3 = __builtin_amdgcn_readfirstlane(p3.x), t3 = __builtin_amdgcn_readfirstlane(p3.y);
    EDGE_BODY(s0, t0)
    EDGE_BODY(s1, t1)
    EDGE_BODY(s2, t2)
    EDGE_BODY(s3, t3)
  }
  for (; e < hi; ++e) {
    int2 p = csr_se[e];
    int s0 = __builtin_amdgcn_readfirstlane(p.x), t0 = __builtin_amdgcn_readfirstlane(p.y);
    EDGE_BODY(s0, t0)
  }
#undef EDGE_BODY

  float inv = 1.0f / (float)(deg > 0 ? deg : 1);
  unsigned short* out = Abuf + (size_t)node * KDIM;
  unsigned p0w = (unsigned)f2b(a0.x * inv) | ((unsigned)f2b(a0.y * inv) << 16);
  unsigned p1w = (unsigned)f2b(a1.x * inv) | ((unsigned)f2b(a1.y * inv) << 16);
  unsigned p2w = (unsigned)f2b(a2.x * inv) | ((unsigned)f2b(a2.y * inv) << 16);
  unsigned p3w = (unsigned)f2b(a3.x * inv) | ((unsigned)f2b(a3.y * inv) << 16);
  *reinterpret_cast<unsigned*>(out + 0 * 128 + laneoff) = p0w;
  *reinterpret_cast<unsigned*>(out + 1 * 128 + laneoff) = p1w;
  *reinterpret_cast<unsigned*>(out + 2 * 128 + laneoff) = p2w;
  *reinterpret_cast<unsigned*>(out + 3 * 128 + laneoff) = p3w;
}

// ---------------- layer-2 aggregation over projected features
// P[n,c] = Abuf[n*640 + c], c in [0,80): c<64 -> (h.basis2[b=c>>4])[o=c&15], c>=64 -> h.loop_w2[c-64]
// out[d,o] = (1/deg)*sum_e sum_b comp2[et,b]*P[src,b*16+o] + P[d,64+o] + bias2[o]
__global__ __launch_bounds__(256) void agg2_kernel(const int* __restrict__ csr_start,
                                                   const int* __restrict__ csr_cnt,
                                                   const int2* __restrict__ csr_se,
                                                   const float* __restrict__ comp,
                                                   const unsigned short* __restrict__ Abuf,
                                                   const float* __restrict__ bias2,
                                                   float* __restrict__ dout) {
  int node = blockIdx.x * 4 + (threadIdx.x >> 6);
  if (node >= N_NODES) return;
  int lane = threadIdx.x & 63;
  int bsel = lane >> 4;  // which basis this lane accumulates
  int o = lane & 15;
  int lo = __builtin_amdgcn_readfirstlane(csr_start[node]);
  int deg = __builtin_amdgcn_readfirstlane(csr_cnt[node]);
  int hi = lo + deg;

  float acc = 0.f;

#define EDGE2_BODY(S, T)                                                   \
  {                                                                        \
    unsigned short u = Abuf[(size_t)(S)*KDIM + lane];                      \
    float4 c = *reinterpret_cast<const float4*>(comp + (T)*4);             \
    float cb = (bsel < 2) ? ((bsel == 0) ? c.x : c.y)                      \
                          : ((bsel == 2) ? c.z : c.w);                     \
    acc = fmaf(cb, b2f(u), acc);                                           \
  }

  int e = lo;
  for (; e + 4 <= hi; e += 4) {
    int2 p0 = csr_se[e], p1 = csr_se[e + 1], p2 = csr_se[e + 2], p3 = csr_se[e + 3];
    int s0 = __builtin_amdgcn_readfirstlane(p0.x), t0 = __builtin_amdgcn_readfirstlane(p0.y);
    int s1 = __builtin_amdgcn_readfirstlane(p1.x), t1 = __builtin_amdgcn_readfirstlane(p1.y);
    int s2 = __builtin_amdgcn_readfirstlane(p2.x), t2 = __builtin_amdgcn_readfirstlane(p2.y);
    int s3 = __builtin_amdgcn_readfirstlane(p3.x), t3 = __builtin_amdgcn_readfirstlane(p3.y);
    EDGE2_BODY(s0, t0)
    EDGE2_BODY(s1, t1)
    EDGE2_BODY(s2, t2)
    EDGE2_BODY(s3, t3)
  }
  for (; e < hi; ++e) {
    int2 p = csr_se[e];
    int s0 = __builtin_amdgcn_readfirstlane(p.x), t0 = __builtin_amdgcn_readfirstlane(p.y);
    EDGE2_BODY(s0, t0)
  }
#undef EDGE2_BODY

  // reduce the 4 basis groups: lanes 0..15 end with the total
  acc += __shfl_xor(acc, 16, 64);
  acc += __shfl_xor(acc, 32, 64);

  if (lane < 16) {
    float inv = 1.0f / (float)(deg > 0 ? deg : 1);
    float sl = b2f(Abuf[(size_t)node * KDIM + 64 + o]);
    dout[(size_t)node * OUT_DIM + o] = acc * inv + sl + bias2[o];
  }
}

// ---------------- GEMM: C[M,NC] = A[M,KT] * Bt[NC,KT]^T (+bias, opt relu), bf16 out
template <int NC, int KT, bool RELU, bool HAS_BIAS>
__global__ __launch_bounds__(256) void gemm_kernel(const unsigned short* __restrict__ A,
                                                   int a_stride,
                                                   const unsigned short* __restrict__ Bt,
                                                   int bt_stride,
                                                   const float* __restrict__ bias,
                                                   unsigned short* __restrict__ outp,
                                                   int out_stride, int M) {
  __shared__ unsigned short As[64][64];
  __shared__ unsigned short Bs[NC][64];
  int wave = threadIdx.x >> 6;
  int lane = threadIdx.x & 63;
  int row0 = blockIdx.x * 64;
  f32x4 acc[NC / 16];
#pragma unroll
  for (int i = 0; i < NC / 16; ++i) acc[i] = (f32x4){0.f, 0.f, 0.f, 0.f};

  int ar = wave * 16 + (lane & 15);
  int kh = lane >> 4;  // 0..3, selects k-octet within K=32

  for (int k0 = 0; k0 < KT; k0 += 64) {
#pragma unroll
    for (int p = 0; p < 2; ++p) {
      int cid = threadIdx.x + p * 256;
      int r = cid >> 3, c8 = cid & 7;
      int gr = row0 + r;
      short8 v = {};
      if (gr < M) v = *reinterpret_cast<const short8*>(A + (size_t)gr * a_stride + k0 + c8 * 8);
      *reinterpret_cast<short8*>(&As[r][(c8 ^ (r & 7)) * 8]) = v;
    }
    for (int cid = threadIdx.x; cid < NC * 8; cid += 256) {
      int r = cid >> 3, c8 = cid & 7;
      short8 v = *reinterpret_cast<const short8*>(Bt + (size_t)r * bt_stride + k0 + c8 * 8);
      *reinterpret_cast<short8*>(&Bs[r][(c8 ^ (r & 7)) * 8]) = v;
    }
    __syncthreads();
    short8 a0 = *reinterpret_cast<const short8*>(&As[ar][((kh) ^ (ar & 7)) * 8]);
    short8 a1 = *reinterpret_cast<const short8*>(&As[ar][((4 + kh) ^ (ar & 7)) * 8]);
#pragma unroll
    for (int ct = 0; ct < NC / 16; ++ct) {
      int bc = ct * 16 + (lane & 15);
      short8 b0 = *reinterpret_cast<const short8*>(&Bs[bc][((kh) ^ (bc & 7)) * 8]);
      short8 b1 = *reinterpret_cast<const short8*>(&Bs[bc][((4 + kh) ^ (bc & 7)) * 8]);
      acc[ct] = __builtin_amdgcn_mfma_f32_16x16x32_bf16(a0, b0, acc[ct], 0, 0, 0);
      acc[ct] = __builtin_amdgcn_mfma_f32_16x16x32_bf16(a1, b1, acc[ct], 0, 0, 0);
    }
    __syncthreads();
  }
  int col_l = lane & 15;
  int rb = row0 + wave * 16 + (lane >> 4) * 4;
#pragma unroll
  for (int ct = 0; ct < NC / 16; ++ct) {
    int col = ct * 16 + col_l;
    float bv = HAS_BIAS ? bias[col] : 0.f;
#pragma unroll
    for (int r = 0; r < 4; ++r) {
      int gr = rb + r;
      if (gr < M) {
        float v = acc[ct][r] + bv;
        if (RELU) v = fmaxf(v, 0.0f);
        outp[(size_t)gr * out_stride + col] = f2b(v);
      }
    }
  }
}

extern "C" void kernel_launch(void* const* d_in, const int* in_sizes, int n_in,
                              void* d_out, int out_size, void* d_ws, size_t ws_size,
                              hipStream_t stream) {
  const int* node_ids = (const int*)d_in[0];
  const int* src = (const int*)d_in[1];
  const int* dst = (const int*)d_in[2];
  const int* etype = (const int*)d_in[3];
  const float* emb = (const float*)d_in[4];
  const float* basis1 = (const float*)d_in[5];
  const float* comp1 = (const float*)d_in[6];
  const float* loop_w1 = (const float*)d_in[7];
  const float* bias1 = (const float*)d_in[8];
  const float* basis2 = (const float*)d_in[9];
  const float* comp2 = (const float*)d_in[10];
  const float* loop_w2 = (const float*)d_in[11];
  const float* bias2 = (const float*)d_in[12];
  (void)in_sizes; (void)n_in; (void)out_size; (void)ws_size;

  char* ws = (char*)d_ws;
  size_t off = 0;
  auto alloc = [&](size_t bytes) -> void* {
    void* p = ws + off;
    off += (bytes + 255) & ~(size_t)255;
    return p;
  };
  int* csr_start = (int*)alloc(N_NODES * sizeof(int));
  int* cntA = (int*)alloc(N_NODES * sizeof(int));
  int* cntB = (int*)alloc(N_NODES * sizeof(int));
  int* counter = (int*)alloc(sizeof(int));
  int2* csr_se = (int2*)alloc((size_t)N_EDGES * sizeof(int2));
  unsigned short* Abuf = (unsigned short*)alloc((size_t)N_NODES * KDIM * sizeof(unsigned short));
  unsigned short* B1t = (unsigned short*)alloc(128 * KDIM * sizeof(unsigned short));
  unsigned short* B2pt = (unsigned short*)alloc(80 * 128 * sizeof(unsigned short));

  prologue_kernel<<<CONV_BLOCKS + PREP_BLOCKS + INIT_BLOCKS, 256, 0, stream>>>(
      node_ids, emb, Abuf, basis1, loop_w1, basis2, loop_w2, B1t, B2pt, cntA, cntB, counter);
  count_kernel<<<1024, 256, 0, stream>>>(dst, cntA);
  alloc_kernel<<<(N_NODES + 255) / 256, 256, 0, stream>>>(cntA, csr_start, counter);
  fill_kernel<<<1024, 256, 0, stream>>>(src, dst, etype, csr_start, cntB, csr_se);

  // layer 1: aggregate x -> y1s (Abuf cols 0:512), then h = relu([y1s|x]*B1 + bias1) -> cols 512:640
  agg_kernel<<<(N_NODES + 3) / 4, 256, 0, stream>>>(csr_start, cntA, csr_se, comp1, Abuf);
  gemm_kernel<128, KDIM, true, true><<<(N_NODES + 63) / 64, 256, 0, stream>>>(
      Abuf, KDIM, B1t, KDIM, bias1, Abuf + 512, KDIM, N_NODES);

  // layer 2 (projection-first): P[n,0:80] = h[n]*[basis2|loop_w2] -> Abuf cols 0:80,
  // then agg over P + self-loop + bias2 -> d_out (fp32)
  gemm_kernel<80, 128, false, false><<<(N_NODES + 63) / 64, 256, 0, stream>>>(
      Abuf + 512, KDIM, B2pt, 128, nullptr, Abuf, KDIM, N_NODES);
  agg2_kernel<<<(N_NODES + 3) / 4, 256, 0, stream>>>(csr_start, cntA, csr_se, comp2, Abuf,
                                                     bias2, (float*)d_out);
}